// Round 1
// baseline (1216.179 us; speedup 1.0000x reference)
//
#include <hip/hip_runtime.h>
#include <math.h>

typedef __bf16 bf16;
typedef __bf16 bf16x8 __attribute__((ext_vector_type(8)));
typedef float  f32x4  __attribute__((ext_vector_type(4)));

#define MFMA16(a,b,c) __builtin_amdgcn_mfma_f32_16x16x32_bf16((a),(b),(c),0,0,0)

#define B_SZ 4096
#define T_SZ 200
#define D_SZ 128
#define U_SZ 128
#define CHUNK 4

__device__ __forceinline__ float sigmoidf_(float x) { return 1.0f / (1.0f + expf(-x)); }
// dice with moving_mean=0, moving_var=1: x_norm == x exactly (1/sqrt(1+1e-9) rounds to 1.0f)
__device__ __forceinline__ float dicef(float x, float alpha) {
    float p = 1.0f / (1.0f + expf(-x));
    return alpha * (1.0f - p) * x + p * x;
}

// ---------------------------------------------------------------------------
// Kernel 1: attention scores.  One block per batch element b, covers all T.
// h1 = dice(bias1 + x@W1' + (q*x)@W1'' ), h2 = dice(h1@W2), s = h2@W3,
// att[b,t] = t<len ? sigmoid(s) : 0
// ---------------------------------------------------------------------------
__global__ __launch_bounds__(256, 2) void attn_kernel(
    const float* __restrict__ X,    // [B,T,D]
    const float* __restrict__ Q,    // [B,D]
    const int*   __restrict__ LEN,  // [B,1]
    const float* __restrict__ W1,   // [512,64]
    const float* __restrict__ A1,   // [64]
    const float* __restrict__ W2,   // [64,16]
    const float* __restrict__ A2,   // [16]
    const float* __restrict__ W3,   // [16,1]
    float* __restrict__ ATT)        // [B,T]
{
    __shared__ bf16  W1p[64][264];   // combined weights, stored [n][k], k<128: W1b-W1c, k>=128: W1d
    __shared__ bf16  H1s[64][72];    // per-wave 16-row dice(h1) buffer (wave w rows w*16..)
    __shared__ bf16  W2t[16][72];    // [n][k]
    __shared__ float qf[128];
    __shared__ float bias1[64];
    __shared__ float bpart[4][64];
    __shared__ float al1[64];
    __shared__ float al2[16];
    __shared__ float w3s[16];

    const int tid  = threadIdx.x;
    const int b    = blockIdx.x;
    const int lane = tid & 63;
    const int w    = tid >> 6;
    const int quad = lane >> 4;
    const int l15  = lane & 15;
    const int len  = LEN[b];

    if (tid < 128) qf[tid] = Q[(long)b * D_SZ + tid];
    if (tid < 64)  al1[tid] = A1[tid];
    if (tid < 16) { al2[tid] = A2[tid]; w3s[tid] = W3[tid]; }

    // stage combined W1' -> LDS [n][k]
    #pragma unroll 4
    for (int it = 0; it < 64; ++it) {
        int idx = it * 256 + tid;       // 0..16383
        int k = idx >> 6;               // 0..255
        int n = idx & 63;
        float v;
        if (k < 128) v = W1[(128 + k) * 64 + n] - W1[(256 + k) * 64 + n];
        else         v = W1[(384 + (k - 128)) * 64 + n];
        W1p[n][k] = (bf16)v;
    }
    // stage W2^T
    #pragma unroll
    for (int it = 0; it < 4; ++it) {
        int idx = it * 256 + tid; int k = idx >> 4; int n = idx & 15;
        W2t[n][k] = (bf16)W2[k * 16 + n];
    }
    __syncthreads();

    // bias1[n] = sum_f q[f]*(W1a[f][n] + W1c[f][n]), split over 4 f-segments
    {
        int n = tid & 63; int seg = tid >> 6;
        float s = 0.f;
        for (int f = seg * 32; f < seg * 32 + 32; ++f)
            s += qf[f] * (W1[f * 64 + n] + W1[(256 + f) * 64 + n]);
        bpart[seg][n] = s;
    }
    __syncthreads();
    if (tid < 64) bias1[tid] = bpart[0][tid] + bpart[1][tid] + bpart[2][tid] + bpart[3][tid];
    __syncthreads();

    // register-cache B fragments
    bf16x8 b1[4][8];
    #pragma unroll
    for (int nt = 0; nt < 4; ++nt)
        #pragma unroll
        for (int kk = 0; kk < 8; ++kk)
            b1[nt][kk] = *(const bf16x8*)&W1p[nt * 16 + l15][kk * 32 + quad * 8];
    bf16x8 b2[2];
    #pragma unroll
    for (int kk = 0; kk < 2; ++kk)
        b2[kk] = *(const bf16x8*)&W2t[l15][kk * 32 + quad * 8];

    // M loop: wave w handles tiles w, w+4, w+8, w+12 (13 tiles cover 208 rows)
    for (int mt = w; mt < 13; mt += 4) {
        const int m0 = mt * 16;
        const int row = m0 + l15;
        const int rclamp = row < T_SZ ? row : (T_SZ - 1);
        const float* xp = X + ((long)b * T_SZ + rclamp) * D_SZ;

        f32x4 acc[4] = {};
        #pragma unroll
        for (int kc = 0; kc < 4; ++kc) {
            const float* p = xp + kc * 32 + quad * 8;
            float4 xa = ((const float4*)p)[0];
            float4 xb = ((const float4*)p)[1];
            float xv[8] = {xa.x, xa.y, xa.z, xa.w, xb.x, xb.y, xb.z, xb.w};
            const float4* qp = (const float4*)&qf[kc * 32 + quad * 8];
            float4 qa = qp[0], qb4 = qp[1];
            float qv[8] = {qa.x, qa.y, qa.z, qa.w, qb4.x, qb4.y, qb4.z, qb4.w};
            bf16x8 a_x, a_qx;
            #pragma unroll
            for (int j = 0; j < 8; ++j) {
                a_x[j]  = (bf16)xv[j];
                a_qx[j] = (bf16)(xv[j] * qv[j]);
            }
            #pragma unroll
            for (int nt = 0; nt < 4; ++nt) {
                acc[nt] = MFMA16(a_x,  b1[nt][kc],     acc[nt]);
                acc[nt] = MFMA16(a_qx, b1[nt][kc + 4], acc[nt]);
            }
        }
        // dice -> H1s (bf16, A-layout rows local to wave)
        #pragma unroll
        for (int nt = 0; nt < 4; ++nt) {
            int n = nt * 16 + l15;
            float bia = bias1[n]; float al = al1[n];
            #pragma unroll
            for (int i = 0; i < 4; ++i) {
                float v = acc[nt][i] + bia;
                H1s[w * 16 + quad * 4 + i][n] = (bf16)dicef(v, al);
            }
        }
        // GEMM2: (16x64)@(64x16)
        f32x4 acc2 = {};
        #pragma unroll
        for (int kk = 0; kk < 2; ++kk) {
            bf16x8 a2 = *(const bf16x8*)&H1s[w * 16 + l15][kk * 32 + quad * 8];
            acc2 = MFMA16(a2, b2[kk], acc2);
        }
        // dice, dot W3, reduce over the 16 columns, write att
        {
            float al = al2[l15]; float w3 = w3s[l15];
            float s[4];
            #pragma unroll
            for (int i = 0; i < 4; ++i) s[i] = dicef(acc2[i], al) * w3;
            #pragma unroll
            for (int i = 0; i < 4; ++i) {
                s[i] += __shfl_xor(s[i], 1, 64);
                s[i] += __shfl_xor(s[i], 2, 64);
                s[i] += __shfl_xor(s[i], 4, 64);
                s[i] += __shfl_xor(s[i], 8, 64);
            }
            if (l15 == 0) {
                #pragma unroll
                for (int i = 0; i < 4; ++i) {
                    int t = m0 + quad * 4 + i;
                    if (t < T_SZ)
                        ATT[(long)b * T_SZ + t] = (t < len) ? sigmoidf_(s[i]) : 0.0f;
                }
            }
        }
    }
}

// ---------------------------------------------------------------------------
// Kernel 2: AUGRU recurrence. One block per 16 batch rows, 200 steps.
// All 6 weight blocks live in registers as MFMA B-fragments.
// h kept fp32 in LDS (Hf); bf16 mirror (Hb) only as MFMA input.
// ---------------------------------------------------------------------------
__global__ __launch_bounds__(256, 1) void augru_kernel(
    const float* __restrict__ X,    // [B,T,D]
    const float* __restrict__ ATT,  // [B,T]
    const float* __restrict__ WU,   // [256,128]
    const float* __restrict__ WR,
    const float* __restrict__ WC,
    float* __restrict__ OUT)        // [B,128]
{
    __shared__ bf16  Xs[2][CHUNK][16][136];
    __shared__ float As[2][CHUNK][16];
    __shared__ bf16  Hb[16][136];
    __shared__ bf16  RHb[16][136];
    __shared__ float Hf[16][132];

    const int tid  = threadIdx.x;
    const int lane = tid & 63;
    const int w    = tid >> 6;
    const int quad = lane >> 4;
    const int l15  = lane & 15;
    const int b0   = blockIdx.x * 16;

    for (int i = tid; i < 16 * 136; i += 256) {
        Hb[i / 136][i % 136]  = (bf16)0.f;
        RHb[i / 136][i % 136] = (bf16)0.f;
    }
    for (int i = tid; i < 16 * 132; i += 256) Hf[i / 132][i % 132] = 0.f;

    // weight fragments: Wf[gate][part(0=x,1=h)][nt][kk], wave w owns cols w*32..w*32+31
    bf16x8 Wf[3][2][2][4];
    {
        const float* Wg[3] = {WU, WR, WC};
        #pragma unroll
        for (int g = 0; g < 3; ++g)
            #pragma unroll
            for (int p = 0; p < 2; ++p)
                #pragma unroll
                for (int nt = 0; nt < 2; ++nt)
                    #pragma unroll
                    for (int kk = 0; kk < 4; ++kk) {
                        int n = w * 32 + nt * 16 + l15;
                        #pragma unroll
                        for (int i = 0; i < 8; ++i) {
                            int k = p * 128 + kk * 32 + quad * 8 + i;
                            Wf[g][p][nt][kk][i] = (bf16)Wg[g][k * 128 + n];
                        }
                    }
    }

    float4 pf[CHUNK * 2];
    float  pa = 0.f;
    auto issue_loads = [&](int c) {
        #pragma unroll
        for (int it = 0; it < CHUNK * 2; ++it) {
            int gidx = it * 256 + tid;
            int c4 = gidx & 31;
            int pair = gidx >> 5;
            int r = pair & 15;
            int s = pair >> 4;
            pf[it] = *(const float4*)(X + ((long)(b0 + r) * T_SZ + (c * CHUNK + s)) * D_SZ + c4 * 4);
        }
        if (tid < CHUNK * 16) {
            int r = tid & 15; int s = tid >> 4;
            pa = ATT[(long)(b0 + r) * T_SZ + c * CHUNK + s];
        }
    };
    auto commit = [&](int buf) {
        #pragma unroll
        for (int it = 0; it < CHUNK * 2; ++it) {
            int gidx = it * 256 + tid;
            int c4 = gidx & 31;
            int pair = gidx >> 5;
            int r = pair & 15;
            int s = pair >> 4;
            bf16* dst = &Xs[buf][s][r][c4 * 4];
            float4 v = pf[it];
            dst[0] = (bf16)v.x; dst[1] = (bf16)v.y; dst[2] = (bf16)v.z; dst[3] = (bf16)v.w;
        }
        if (tid < CHUNK * 16) { int r = tid & 15; int s = tid >> 4; As[buf][s][r] = pa; }
    };

    issue_loads(0);
    commit(0);
    __syncthreads();

    const int NCH = T_SZ / CHUNK;   // 50
    for (int c = 0; c < NCH; ++c) {
        const int buf = c & 1;
        if (c + 1 < NCH) issue_loads(c + 1);

        #pragma unroll
        for (int s = 0; s < CHUNK; ++s) {
            bf16x8 ax[4], ah[4];
            #pragma unroll
            for (int kk = 0; kk < 4; ++kk) {
                ax[kk] = *(const bf16x8*)&Xs[buf][s][l15][kk * 32 + quad * 8];
                ah[kk] = *(const bf16x8*)&Hb[l15][kk * 32 + quad * 8];
            }
            f32x4 pu[2] = {}, pr[2] = {};
            #pragma unroll
            for (int nt = 0; nt < 2; ++nt)
                #pragma unroll
                for (int kk = 0; kk < 4; ++kk) {
                    pu[nt] = MFMA16(ax[kk], Wf[0][0][nt][kk], pu[nt]);
                    pu[nt] = MFMA16(ah[kk], Wf[0][1][nt][kk], pu[nt]);
                    pr[nt] = MFMA16(ax[kk], Wf[1][0][nt][kk], pr[nt]);
                    pr[nt] = MFMA16(ah[kk], Wf[1][1][nt][kk], pr[nt]);
                }
            float hc[2][4], uu[2][4];
            #pragma unroll
            for (int nt = 0; nt < 2; ++nt) {
                int n = w * 32 + nt * 16 + l15;
                #pragma unroll
                for (int i = 0; i < 4; ++i) {
                    int row = quad * 4 + i;
                    float h = Hf[row][n];
                    hc[nt][i] = h;
                    uu[nt][i] = sigmoidf_(pu[nt][i]);
                    float rr = sigmoidf_(pr[nt][i]);
                    RHb[row][n] = (bf16)(rr * h);
                }
            }
            __syncthreads();
            bf16x8 ar[4];
            #pragma unroll
            for (int kk = 0; kk < 4; ++kk)
                ar[kk] = *(const bf16x8*)&RHb[l15][kk * 32 + quad * 8];
            f32x4 pc[2] = {};
            #pragma unroll
            for (int nt = 0; nt < 2; ++nt)
                #pragma unroll
                for (int kk = 0; kk < 4; ++kk) {
                    pc[nt] = MFMA16(ax[kk], Wf[2][0][nt][kk], pc[nt]);
                    pc[nt] = MFMA16(ar[kk], Wf[2][1][nt][kk], pc[nt]);
                }
            #pragma unroll
            for (int nt = 0; nt < 2; ++nt) {
                int n = w * 32 + nt * 16 + l15;
                #pragma unroll
                for (int i = 0; i < 4; ++i) {
                    int row = quad * 4 + i;
                    float a = As[buf][s][row];
                    float cg = tanhf(pc[nt][i]);
                    float ut = uu[nt][i] * a;
                    float hn = (1.f - ut) * hc[nt][i] + ut * cg;
                    Hf[row][n] = hn;
                    Hb[row][n] = (bf16)hn;
                }
            }
            __syncthreads();
        }
        if (c + 1 < NCH) commit(buf ^ 1);
        __syncthreads();
    }

    // write h_final
    {
        int r = tid >> 4; int c8 = (tid & 15) * 8;
        #pragma unroll
        for (int j = 0; j < 8; ++j)
            OUT[(long)(b0 + r) * U_SZ + c8 + j] = Hf[r][c8 + j];
    }
}

extern "C" void kernel_launch(void* const* d_in, const int* in_sizes, int n_in,
                              void* d_out, int out_size, void* d_ws, size_t ws_size,
                              hipStream_t stream) {
    const float* X   = (const float*)d_in[0];
    const float* Q   = (const float*)d_in[1];
    const int*   LEN = (const int*)d_in[2];
    const float* W1  = (const float*)d_in[3];
    const float* A1  = (const float*)d_in[4];
    const float* W2  = (const float*)d_in[5];
    const float* A2  = (const float*)d_in[6];
    const float* W3  = (const float*)d_in[7];
    const float* WU  = (const float*)d_in[8];
    const float* WR  = (const float*)d_in[9];
    const float* WC  = (const float*)d_in[10];
    float* OUT = (float*)d_out;
    float* ATT = (float*)d_ws;   // B*T floats = 3.3 MB scratch

    attn_kernel<<<B_SZ, 256, 0, stream>>>(X, Q, LEN, W1, A1, W2, A2, W3, ATT);
    augru_kernel<<<B_SZ / 16, 256, 0, stream>>>(X, ATT, WU, WR, WC, OUT);
}